// Round 5
// baseline (316.858 us; speedup 1.0000x reference)
//
#include <hip/hip_runtime.h>
#include <hip/hip_bf16.h>
#include <math.h>

#define NN     8192
#define NIN    64
#define NH     128
#define MAXD   128
#define NTRAIN 4096
#define NSAMP  8192
#define ROWCHUNK 32

typedef __attribute__((ext_vector_type(8))) short short8;
typedef __attribute__((ext_vector_type(4))) float f32x4;

__device__ __forceinline__ float dot4(float4 a, float4 b) {
    return a.x*b.x + a.y*b.y + a.z*b.z + a.w*b.w;
}

// K1 (fused lin1+lin2): per row r:
//   h = relu(seq1 W_stru^T + b_stru); xa = relu(seq1 W_a1^T + b_a1)  [LDS only]
//   hp = h W_gat^T; a_s/a_d = hp.att; x_ = xa W_a2^T + b_a2; attr_err = ||seq1-x_||
// Also zeroes cnt/cntc/samp_sum/out[0] (replaces memset nodes).
__global__ __launch_bounds__(128) void k_fused_lin(
    const float* __restrict__ seq1, const float* __restrict__ W_stru,
    const float* __restrict__ b_stru, const float* __restrict__ W_a1,
    const float* __restrict__ b_a1, const float* __restrict__ W_gat,
    const float* __restrict__ att_src, const float* __restrict__ att_dst,
    const float* __restrict__ W_a2, const float* __restrict__ b_a2,
    float* __restrict__ hp, float* __restrict__ a_s, float* __restrict__ a_d,
    float* __restrict__ attr_err, int* __restrict__ cnt, int* __restrict__ cntc,
    float* __restrict__ samp_sum, float* __restrict__ out)
{
    __shared__ float hrow[NH], xrow[NH], srow[NIN];
    int r = blockIdx.x, t = threadIdx.x;   // 128 threads
    if (t == 0) {
        cnt[r] = 0; cntc[r] = 0; samp_sum[r] = 0.f;
        if (r == 0) out[0] = 0.f;
    }
    if (t < NIN) srow[t] = seq1[(size_t)r*NIN + t];
    __syncthreads();
    // phase 1: t = hidden unit 0..127
    {
        const float4* w1 = (const float4*)(W_stru + (size_t)t*NIN);
        const float4* w2 = (const float4*)(W_a1  + (size_t)t*NIN);
        const float4* s4 = (const float4*)srow;
        float s1 = 0.f, s2 = 0.f;
#pragma unroll
        for (int k = 0; k < NIN/4; ++k) {
            float4 sv = s4[k];
            s1 += dot4(sv, w1[k]);
            s2 += dot4(sv, w2[k]);
        }
        hrow[t] = fmaxf(s1 + b_stru[t], 0.f);
        xrow[t] = fmaxf(s2 + b_a1[t],  0.f);
    }
    __syncthreads();
    // phase 2: wave 0 only, t = out dim 0..63
    if (t < 64) {
        const float4* wg = (const float4*)(W_gat + (size_t)t*NH);
        const float4* wa = (const float4*)(W_a2  + (size_t)t*NH);
        const float4* h4 = (const float4*)hrow;
        const float4* x4 = (const float4*)xrow;
        float hv = 0.f, xv = 0.f;
#pragma unroll
        for (int k = 0; k < NH/4; ++k) {
            hv += dot4(h4[k], wg[k]);
            xv += dot4(x4[k], wa[k]);
        }
        hp[(size_t)r*NIN + t] = hv;
        float asv = hv * att_src[t];
        float adv = hv * att_dst[t];
        float d   = srow[t] - (xv + b_a2[t]);
        float de  = d * d;
#pragma unroll
        for (int o = 32; o > 0; o >>= 1) {
            asv += __shfl_xor(asv, o);
            adv += __shfl_xor(adv, o);
            de  += __shfl_xor(de,  o);
        }
        if (t == 0) {
            a_s[r] = asv;
            a_d[r] = adv;
            attr_err[r] = sqrtf(de);
        }
    }
}

// K2: pure streaming scan of adj (uint4 = 4 columns/thread), emitting
// per-row and per-column nonzero lists via atomics. 99.8% zeros, so the
// hot path is load + OR + compare. 2048 blocks = 524K threads.
__global__ __launch_bounds__(256) void k_scan(const float* __restrict__ adj,
                       int* __restrict__ cnt, int* __restrict__ nzlist,
                       int* __restrict__ cntc, int* __restrict__ listc)
{
    int j4 = blockIdx.x * 256 + threadIdx.x;     // float4-column index
    int i0 = blockIdx.y * ROWCHUNK;
    const uint4* base = (const uint4*)adj + (size_t)i0 * (NN/4) + j4;
    for (int ib = 0; ib < ROWCHUNK; ib += 8) {
        uint4 v[8];
#pragma unroll
        for (int u = 0; u < 8; ++u)
            v[u] = base[(size_t)(ib + u) * (NN/4)];
#pragma unroll
        for (int u = 0; u < 8; ++u) {
            if (v[u].x | v[u].y | v[u].z | v[u].w) {
                int i = i0 + ib + u;
                unsigned vals[4] = {v[u].x, v[u].y, v[u].z, v[u].w};
#pragma unroll
                for (int e = 0; e < 4; ++e) {
                    if (vals[e]) {
                        int j = j4 * 4 + e;
                        int p = atomicAdd(&cnt[i], 1);
                        if (p < MAXD) nzlist[(size_t)i*MAXD + p] = j;
                        int q = atomicAdd(&cntc[j], 1);
                        if (q < MAXD) listc[(size_t)j*MAXD + q] = i;
                    }
                }
            }
        }
    }
}

// K3: per-column softmax + weighted feature sum over the sparse source list
// (plus the GATConv self-loop). One wave per column; lane = feature dim.
__global__ void k_softmax_col(const float* __restrict__ hp, const float* __restrict__ a_s,
                              const float* __restrict__ a_d, const int* __restrict__ cntc,
                              const int* __restrict__ listc, const float* __restrict__ b_gat,
                              float* __restrict__ emb, __hip_bfloat16* __restrict__ embb)
{
    int j = blockIdx.x * 4 + (threadIdx.x >> 6);
    int lane = threadIdx.x & 63;
    float adv = a_d[j];
    // self loop (diagonal of adj is zero by construction, so no double count)
    float x = a_s[j] + adv;
    float e = x > 0.f ? x : 0.2f * x;
    float w = __expf(e);
    float den = w;
    float acc = w * hp[(size_t)j*NIN + lane];
    int c = cntc[j]; if (c > MAXD) c = MAXD;
    for (int t = 0; t < c; ++t) {
        int i = listc[(size_t)j*MAXD + t];
        float xi = a_s[i] + adv;
        float ei = xi > 0.f ? xi : 0.2f * xi;
        float wi = __expf(ei);
        den += wi;
        acc += wi * hp[(size_t)i*NIN + lane];
    }
    float v = acc / den + b_gat[lane];
    emb [(size_t)j*NIN + lane] = v;
    embb[(size_t)j*NIN + lane] = __float2bfloat16(v);
}

// K4: samp_sum[r] += sum_j sigmoid(emb[sel[r]] . emb[j])^2 via bf16 MFMA.
// Wave owns 16 sample rows; A,B frags loaded straight from row-major bf16
// (lane: row l&15, k-slice (l>>4)*8 — no LDS, no layout shuffle).
// C/D mapping (verified m89): col=lane&15, row=(lane>>4)*4+reg.
__global__ __launch_bounds__(256) void k_score_mfma(const __hip_bfloat16* __restrict__ embb,
                       const int* __restrict__ idx_tr, const int* __restrict__ idx_te,
                       float* __restrict__ samp_sum)
{
    int tid = threadIdx.x;
    int w = tid >> 6, l = tid & 63;
    int lr = l & 15, lk = l >> 4;
    int m_base = blockIdx.x * 64 + w * 16;
    int r = m_base + lr;
    int row = r < NTRAIN ? idx_tr[r] : idx_te[r - NTRAIN];
    const short8* arow = (const short8*)(embb + (size_t)row * NIN);
    short8 a0 = arow[lk];
    short8 a1 = arow[lk + 4];
    f32x4 racc = {0.f, 0.f, 0.f, 0.f};
    int n_start = blockIdx.y * 1024;
    for (int nt = 0; nt < 64; ++nt) {
        int brow = n_start + nt * 16 + lr;
        const short8* bptr = (const short8*)(embb + (size_t)brow * NIN);
        short8 b0 = bptr[lk];
        short8 b1 = bptr[lk + 4];
        f32x4 c = {0.f, 0.f, 0.f, 0.f};
        c = __builtin_amdgcn_mfma_f32_16x16x32_bf16(a0, b0, c, 0, 0, 0);
        c = __builtin_amdgcn_mfma_f32_16x16x32_bf16(a1, b1, c, 0, 0, 0);
#pragma unroll
        for (int q = 0; q < 4; ++q) {
            float sig = __builtin_amdgcn_rcpf(1.f + __expf(-c[q]));
            racc[q] += sig * sig;
        }
    }
#pragma unroll
    for (int off = 1; off < 16; off <<= 1) {
#pragma unroll
        for (int q = 0; q < 4; ++q) racc[q] += __shfl_xor(racc[q], off);
    }
    if (lr == 0) {
#pragma unroll
        for (int q = 0; q < 4; ++q)
            atomicAdd(&samp_sum[m_base + lk * 4 + q], racc[q]);
    }
}

// K5: per sample: stru = sqrt(samp_sum + sum_{nz j}(1-2*sigmoid));
// score -> out[1+k] for test rows, atomic mean into out[0] for train rows.
__global__ void k_final(const float* __restrict__ emb, const float* __restrict__ samp_sum,
                        const float* __restrict__ attr_err, const int* __restrict__ cnt,
                        const int* __restrict__ nzlist, const int* __restrict__ idx_tr,
                        const int* __restrict__ idx_te, float* __restrict__ out)
{
    int r = blockIdx.x * 4 + (threadIdx.x >> 6);
    int lane = threadIdx.x & 63;
    int row = r < NTRAIN ? idx_tr[r] : idx_te[r - NTRAIN];
    float e0 = emb[(size_t)row*NIN + lane];
    int c = cnt[row]; if (c > MAXD) c = MAXD;
    float corr = 0.f;
    for (int e = 0; e < c; ++e) {
        int jj = nzlist[(size_t)row*MAXD + e];
        float v = e0 * emb[(size_t)jj*NIN + lane];
#pragma unroll
        for (int o = 32; o > 0; o >>= 1) v += __shfl_xor(v, o);
        corr += 1.f - 2.f / (1.f + __expf(-v));
    }
    if (lane == 0) {
        float base = samp_sum[r] + corr;
        if (base < 0.f) base = 0.f;
        float sc = 0.5f * attr_err[row] + 0.5f * sqrtf(base);
        if (r < NTRAIN) atomicAdd(out, sc * (1.f / NTRAIN));
        else            out[1 + r - NTRAIN] = sc;
    }
}

extern "C" void kernel_launch(void* const* d_in, const int* in_sizes, int n_in,
                              void* d_out, int out_size, void* d_ws, size_t ws_size,
                              hipStream_t stream)
{
    const float* seq1    = (const float*)d_in[0];
    const float* adj     = (const float*)d_in[1];
    const int*   idx_tr  = (const int*)d_in[2];
    const int*   idx_te  = (const int*)d_in[3];
    const float* W_stru  = (const float*)d_in[4];
    const float* b_stru  = (const float*)d_in[5];
    const float* W_gat   = (const float*)d_in[6];
    const float* att_src = (const float*)d_in[7];
    const float* att_dst = (const float*)d_in[8];
    const float* b_gat   = (const float*)d_in[9];
    const float* W_a1    = (const float*)d_in[10];
    const float* b_a1    = (const float*)d_in[11];
    const float* W_a2    = (const float*)d_in[12];
    const float* b_a2    = (const float*)d_in[13];
    float* out = (float*)d_out;

    char* ws = (char*)d_ws;
    size_t off = 0;
    auto alloc = [&](size_t bytes) {
        size_t p = off;
        off += (bytes + 255) & ~(size_t)255;
        return p;
    };
    float* hp       = (float*)(ws + alloc((size_t)NN*NIN*4));
    float* a_s      = (float*)(ws + alloc((size_t)NN*4));
    float* a_d      = (float*)(ws + alloc((size_t)NN*4));
    float* attr_err = (float*)(ws + alloc((size_t)NN*4));
    float* emb      = (float*)(ws + alloc((size_t)NN*NIN*4));
    __hip_bfloat16* embb = (__hip_bfloat16*)(ws + alloc((size_t)NN*NIN*2));
    int*   cnt      = (int*)  (ws + alloc((size_t)NN*4));
    int*   nzlist   = (int*)  (ws + alloc((size_t)NN*MAXD*4));
    int*   cntc     = (int*)  (ws + alloc((size_t)NN*4));
    int*   listc    = (int*)  (ws + alloc((size_t)NN*MAXD*4));
    float* samp_sum = (float*)(ws + alloc((size_t)NSAMP*4));

    k_fused_lin<<<NN, 128, 0, stream>>>(seq1, W_stru, b_stru, W_a1, b_a1, W_gat,
                                        att_src, att_dst, W_a2, b_a2,
                                        hp, a_s, a_d, attr_err, cnt, cntc, samp_sum, out);
    k_scan<<<dim3((NN/4)/256, NN/ROWCHUNK), 256, 0, stream>>>(adj, cnt, nzlist, cntc, listc);
    k_softmax_col<<<NN/4, 256, 0, stream>>>(hp, a_s, a_d, cntc, listc, b_gat, emb, embb);
    k_score_mfma<<<dim3(NSAMP/64, 8), 256, 0, stream>>>(embb, idx_tr, idx_te, samp_sum);
    k_final<<<NSAMP/4, 256, 0, stream>>>(emb, samp_sum, attr_err, cnt, nzlist,
                                         idx_tr, idx_te, out);
}

// Round 6
// 240.211 us; speedup vs baseline: 1.3191x; 1.3191x over previous
//
#include <hip/hip_runtime.h>
#include <hip/hip_bf16.h>
#include <math.h>

#define NN     8192
#define NIN    64
#define NH     128
#define MAXD   128
#define NTRAIN 4096
#define NSAMP  8192
#define ROWCHUNK 64

typedef __attribute__((ext_vector_type(8))) short short8;
typedef __attribute__((ext_vector_type(4))) float f32x4;

__device__ __forceinline__ float dot4(float4 a, float4 b) {
    return a.x*b.x + a.y*b.y + a.z*b.z + a.w*b.w;
}

// K1 (fused, row-tiled): 512 blocks x 16 rows. Weights live in REGISTERS
// (one row per thread), seq/h/xa staged in LDS -> weight L2 traffic
// 1.5GB -> ~50MB vs the per-row version.
// Phase1: t=(mat,hid 0..127): h/xa = relu(seq W^T + b) -> LDS.
// Phase2: t<128, wave0 = gat (hp, a_s, a_d), wave1 = a2 (attr_err).
// Also zero-inits cnt/cntc/samp_sum/out[0].
__global__ __launch_bounds__(256) void k_lin_fused(
    const float* __restrict__ seq1, const float* __restrict__ W_stru,
    const float* __restrict__ b_stru, const float* __restrict__ W_a1,
    const float* __restrict__ b_a1, const float* __restrict__ W_gat,
    const float* __restrict__ att_src, const float* __restrict__ att_dst,
    const float* __restrict__ W_a2, const float* __restrict__ b_a2,
    float* __restrict__ hp, float* __restrict__ a_s, float* __restrict__ a_d,
    float* __restrict__ attr_err, int* __restrict__ cnt, int* __restrict__ cntc,
    float* __restrict__ samp_sum, float* __restrict__ out)
{
    __shared__ float s_seq[16][NIN];   // 4 KB
    __shared__ float h_lds[16][NH];    // 8 KB
    __shared__ float x_lds[16][NH];    // 8 KB
    int t = threadIdx.x;
    int r0 = blockIdx.x * 16;

    int gid = blockIdx.x * 256 + t;
    if (gid < NN)    { cnt[gid] = 0; cntc[gid] = 0; }
    if (gid < NSAMP) samp_sum[gid] = 0.f;
    if (gid == 0)    out[0] = 0.f;

    // stage 16 seq rows: 1024 floats = 256 float4, one per thread
    ((float4*)&s_seq[0][0])[t] = ((const float4*)(seq1 + (size_t)r0 * NIN))[t];

    // phase-1 weights in registers (64 VGPR)
    int mat = t >> 7, hd = t & 127;
    const float4* Wrow1 = (const float4*)((mat ? W_a1 : W_stru) + (size_t)hd * NIN);
    float4 w1[16];
#pragma unroll
    for (int k = 0; k < 16; ++k) w1[k] = Wrow1[k];
    float b1 = (mat ? b_a1 : b_stru)[hd];
    float* dstl = mat ? &x_lds[0][0] : &h_lds[0][0];
    __syncthreads();

    for (int rl = 0; rl < 16; ++rl) {
        const float4* s4 = (const float4*)&s_seq[rl][0];
        float acc = 0.f;
#pragma unroll
        for (int k = 0; k < 16; ++k) acc += dot4(s4[k], w1[k]);
        dstl[rl * NH + hd] = fmaxf(acc + b1, 0.f);
    }
    __syncthreads();

    if (t < 128) {
        int d = t & 63;
        const float4* Wrow2 = (const float4*)((t < 64 ? W_gat : W_a2) + (size_t)d * NH);
        float4 w2[32];                 // 128 VGPR
#pragma unroll
        for (int k = 0; k < 32; ++k) w2[k] = Wrow2[k];
        float b2   = (t < 64) ? 0.f : b_a2[d];
        float as_c = att_src[d], ad_c = att_dst[d];
        const float* vbase = (t < 64) ? &h_lds[0][0] : &x_lds[0][0];
        for (int rl = 0; rl < 16; ++rl) {
            const float4* v4 = (const float4*)(vbase + rl * NH);
            float acc = 0.f;
#pragma unroll
            for (int k = 0; k < 32; ++k) acc += dot4(v4[k], w2[k]);
            int r = r0 + rl;
            if (t < 64) {
                hp[(size_t)r * NIN + d] = acc;
                float asv = acc * as_c, adv = acc * ad_c;
#pragma unroll
                for (int o = 32; o > 0; o >>= 1) {
                    asv += __shfl_xor(asv, o);
                    adv += __shfl_xor(adv, o);
                }
                if (d == 0) { a_s[r] = asv; a_d[r] = adv; }
            } else {
                float diff = s_seq[rl][d] - (acc + b2);
                float de = diff * diff;
#pragma unroll
                for (int o = 32; o > 0; o >>= 1) de += __shfl_xor(de, o);
                if (d == 0) attr_err[r] = sqrtf(de);
            }
        }
    }
}

// K2: pure streaming scan of adj (uint4 = 4 columns/thread), emitting
// per-row and per-column nonzero lists via atomics. 99.8% zeros.
__global__ __launch_bounds__(256) void k_scan(const float* __restrict__ adj,
                       int* __restrict__ cnt, int* __restrict__ nzlist,
                       int* __restrict__ cntc, int* __restrict__ listc)
{
    int j4 = blockIdx.x * 256 + threadIdx.x;     // float4-column index
    int i0 = blockIdx.y * ROWCHUNK;
    const uint4* base = (const uint4*)adj + (size_t)i0 * (NN/4) + j4;
    for (int ib = 0; ib < ROWCHUNK; ib += 8) {
        uint4 v[8];
#pragma unroll
        for (int u = 0; u < 8; ++u)
            v[u] = base[(size_t)(ib + u) * (NN/4)];
#pragma unroll
        for (int u = 0; u < 8; ++u) {
            if (v[u].x | v[u].y | v[u].z | v[u].w) {
                int i = i0 + ib + u;
                unsigned vals[4] = {v[u].x, v[u].y, v[u].z, v[u].w};
#pragma unroll
                for (int e = 0; e < 4; ++e) {
                    if (vals[e]) {
                        int j = j4 * 4 + e;
                        int p = atomicAdd(&cnt[i], 1);
                        if (p < MAXD) nzlist[(size_t)i*MAXD + p] = j;
                        int q = atomicAdd(&cntc[j], 1);
                        if (q < MAXD) listc[(size_t)j*MAXD + q] = i;
                    }
                }
            }
        }
    }
}

// K3: per-column softmax + weighted feature sum over the sparse source list
// (plus the GATConv self-loop). One wave per column; lane = feature dim.
__global__ void k_softmax_col(const float* __restrict__ hp, const float* __restrict__ a_s,
                              const float* __restrict__ a_d, const int* __restrict__ cntc,
                              const int* __restrict__ listc, const float* __restrict__ b_gat,
                              float* __restrict__ emb, __hip_bfloat16* __restrict__ embb)
{
    int j = blockIdx.x * 4 + (threadIdx.x >> 6);
    int lane = threadIdx.x & 63;
    float adv = a_d[j];
    // self loop (diagonal of adj is zero by construction, so no double count)
    float x = a_s[j] + adv;
    float e = x > 0.f ? x : 0.2f * x;
    float w = __expf(e);
    float den = w;
    float acc = w * hp[(size_t)j*NIN + lane];
    int c = cntc[j]; if (c > MAXD) c = MAXD;
    for (int t = 0; t < c; ++t) {
        int i = listc[(size_t)j*MAXD + t];
        float xi = a_s[i] + adv;
        float ei = xi > 0.f ? xi : 0.2f * xi;
        float wi = __expf(ei);
        den += wi;
        acc += wi * hp[(size_t)i*NIN + lane];
    }
    float v = acc / den + b_gat[lane];
    emb [(size_t)j*NIN + lane] = v;
    embb[(size_t)j*NIN + lane] = __float2bfloat16(v);
}

// K4: samp_sum[r] += sum_j sigmoid(emb[sel[r]] . emb[j])^2 via bf16 MFMA.
// Wave owns 16 sample rows; A,B frags loaded straight from row-major bf16
// (lane: row l&15, k-slice (l>>4)*8 — no LDS, no layout shuffle).
// C/D mapping (verified m89): col=lane&15, row=(lane>>4)*4+reg.
__global__ __launch_bounds__(256) void k_score_mfma(const __hip_bfloat16* __restrict__ embb,
                       const int* __restrict__ idx_tr, const int* __restrict__ idx_te,
                       float* __restrict__ samp_sum)
{
    int tid = threadIdx.x;
    int w = tid >> 6, l = tid & 63;
    int lr = l & 15, lk = l >> 4;
    int m_base = blockIdx.x * 64 + w * 16;
    int r = m_base + lr;
    int row = r < NTRAIN ? idx_tr[r] : idx_te[r - NTRAIN];
    const short8* arow = (const short8*)(embb + (size_t)row * NIN);
    short8 a0 = arow[lk];
    short8 a1 = arow[lk + 4];
    f32x4 racc = {0.f, 0.f, 0.f, 0.f};
    int n_start = blockIdx.y * 1024;
    for (int nt = 0; nt < 64; ++nt) {
        int brow = n_start + nt * 16 + lr;
        const short8* bptr = (const short8*)(embb + (size_t)brow * NIN);
        short8 b0 = bptr[lk];
        short8 b1 = bptr[lk + 4];
        f32x4 c = {0.f, 0.f, 0.f, 0.f};
        c = __builtin_amdgcn_mfma_f32_16x16x32_bf16(a0, b0, c, 0, 0, 0);
        c = __builtin_amdgcn_mfma_f32_16x16x32_bf16(a1, b1, c, 0, 0, 0);
#pragma unroll
        for (int q = 0; q < 4; ++q) {
            float sig = __builtin_amdgcn_rcpf(1.f + __expf(-c[q]));
            racc[q] += sig * sig;
        }
    }
#pragma unroll
    for (int off = 1; off < 16; off <<= 1) {
#pragma unroll
        for (int q = 0; q < 4; ++q) racc[q] += __shfl_xor(racc[q], off);
    }
    if (lr == 0) {
#pragma unroll
        for (int q = 0; q < 4; ++q)
            atomicAdd(&samp_sum[m_base + lk * 4 + q], racc[q]);
    }
}

// K5: per sample: stru = sqrt(samp_sum + sum_{nz j}(1-2*sigmoid));
// score -> out[1+k] for test rows, atomic mean into out[0] for train rows.
__global__ void k_final(const float* __restrict__ emb, const float* __restrict__ samp_sum,
                        const float* __restrict__ attr_err, const int* __restrict__ cnt,
                        const int* __restrict__ nzlist, const int* __restrict__ idx_tr,
                        const int* __restrict__ idx_te, float* __restrict__ out)
{
    int r = blockIdx.x * 4 + (threadIdx.x >> 6);
    int lane = threadIdx.x & 63;
    int row = r < NTRAIN ? idx_tr[r] : idx_te[r - NTRAIN];
    float e0 = emb[(size_t)row*NIN + lane];
    int c = cnt[row]; if (c > MAXD) c = MAXD;
    float corr = 0.f;
    for (int e = 0; e < c; ++e) {
        int jj = nzlist[(size_t)row*MAXD + e];
        float v = e0 * emb[(size_t)jj*NIN + lane];
#pragma unroll
        for (int o = 32; o > 0; o >>= 1) v += __shfl_xor(v, o);
        corr += 1.f - 2.f / (1.f + __expf(-v));
    }
    if (lane == 0) {
        float base = samp_sum[r] + corr;
        if (base < 0.f) base = 0.f;
        float sc = 0.5f * attr_err[row] + 0.5f * sqrtf(base);
        if (r < NTRAIN) atomicAdd(out, sc * (1.f / NTRAIN));
        else            out[1 + r - NTRAIN] = sc;
    }
}

extern "C" void kernel_launch(void* const* d_in, const int* in_sizes, int n_in,
                              void* d_out, int out_size, void* d_ws, size_t ws_size,
                              hipStream_t stream)
{
    const float* seq1    = (const float*)d_in[0];
    const float* adj     = (const float*)d_in[1];
    const int*   idx_tr  = (const int*)d_in[2];
    const int*   idx_te  = (const int*)d_in[3];
    const float* W_stru  = (const float*)d_in[4];
    const float* b_stru  = (const float*)d_in[5];
    const float* W_gat   = (const float*)d_in[6];
    const float* att_src = (const float*)d_in[7];
    const float* att_dst = (const float*)d_in[8];
    const float* b_gat   = (const float*)d_in[9];
    const float* W_a1    = (const float*)d_in[10];
    const float* b_a1    = (const float*)d_in[11];
    const float* W_a2    = (const float*)d_in[12];
    const float* b_a2    = (const float*)d_in[13];
    float* out = (float*)d_out;

    char* ws = (char*)d_ws;
    size_t off = 0;
    auto alloc = [&](size_t bytes) {
        size_t p = off;
        off += (bytes + 255) & ~(size_t)255;
        return p;
    };
    float* hp       = (float*)(ws + alloc((size_t)NN*NIN*4));
    float* a_s      = (float*)(ws + alloc((size_t)NN*4));
    float* a_d      = (float*)(ws + alloc((size_t)NN*4));
    float* attr_err = (float*)(ws + alloc((size_t)NN*4));
    float* emb      = (float*)(ws + alloc((size_t)NN*NIN*4));
    __hip_bfloat16* embb = (__hip_bfloat16*)(ws + alloc((size_t)NN*NIN*2));
    int*   cnt      = (int*)  (ws + alloc((size_t)NN*4));
    int*   nzlist   = (int*)  (ws + alloc((size_t)NN*MAXD*4));
    int*   cntc     = (int*)  (ws + alloc((size_t)NN*4));
    int*   listc    = (int*)  (ws + alloc((size_t)NN*MAXD*4));
    float* samp_sum = (float*)(ws + alloc((size_t)NSAMP*4));

    k_lin_fused<<<NN/16, 256, 0, stream>>>(seq1, W_stru, b_stru, W_a1, b_a1, W_gat,
                                           att_src, att_dst, W_a2, b_a2,
                                           hp, a_s, a_d, attr_err, cnt, cntc, samp_sum, out);
    k_scan<<<dim3((NN/4)/256, NN/ROWCHUNK), 256, 0, stream>>>(adj, cnt, nzlist, cntc, listc);
    k_softmax_col<<<NN/4, 256, 0, stream>>>(hp, a_s, a_d, cntc, listc, b_gat, emb, embb);
    k_score_mfma<<<dim3(NSAMP/64, 8), 256, 0, stream>>>(embb, idx_tr, idx_te, samp_sum);
    k_final<<<NSAMP/4, 256, 0, stream>>>(emb, samp_sum, attr_err, cnt, nzlist,
                                         idx_tr, idx_te, out);
}